// Round 10
// baseline (463.129 us; speedup 1.0000x reference)
//
#include <hip/hip_runtime.h>
#include <hip/hip_bf16.h>

#define TSEQ 2048
#define DM   1024
#define NHD  16
#define DHD  64
#define NEXP 4
#define HIDN 4096
#define NMOE (NEXP*HIDN)   // 16384
#define CHK  128
#define NCHK (TSEQ/CHK)    // 16

typedef __attribute__((ext_vector_type(8))) short          bf16x8_v;  // 8 bf16 = 4 VGPR
typedef __attribute__((ext_vector_type(4))) float          f32x4_v;
typedef __attribute__((ext_vector_type(4))) unsigned short us4_v;

__device__ __forceinline__ unsigned short bfbits(float f) {
  __hip_bfloat16 h = __float2bfloat16(f);
  return __builtin_bit_cast(unsigned short, h);
}
__device__ __forceinline__ float bf2f(unsigned short u) {
  return __uint_as_float(((unsigned)u) << 16);
}
__device__ __forceinline__ float wave_sum(float v) {
  #pragma unroll
  for (int o = 32; o; o >>= 1) v += __shfl_xor(v, o, 64);
  return v;
}
__device__ __forceinline__ void gl_lds16(const void* g, void* l) {
  __builtin_amdgcn_global_load_lds((const __attribute__((address_space(1))) void*)g,
                                   (__attribute__((address_space(3))) void*)l, 16, 0, 0);
}

// ---------------- merged small-weight conversion (pw|qkv|wo|wgate) ----------------
__global__ __launch_bounds__(256) void cvt_all(
    const float* __restrict__ a, unsigned short* __restrict__ oa,   // 1024 blocks
    const float* __restrict__ b, unsigned short* __restrict__ ob,   // 3072 blocks
    const float* __restrict__ c, unsigned short* __restrict__ oc,   // 1024 blocks
    const float* __restrict__ d, unsigned short* __restrict__ od) { // 1024 blocks
  int blk = blockIdx.x;
  const float* in; unsigned short* out; int base;
  if (blk < 1024)      { in = a; out = oa; base = blk; }
  else if (blk < 4096) { in = b; out = ob; base = blk - 1024; }
  else if (blk < 5120) { in = c; out = oc; base = blk - 4096; }
  else                 { in = d; out = od; base = blk - 5120; }
  int i = base * 256 + threadIdx.x;
  float4 v = ((const float4*)in)[i];
  us4_v o; o.x = bfbits(v.x); o.y = bfbits(v.y); o.z = bfbits(v.z); o.w = bfbits(v.w);
  ((us4_v*)out)[i] = o;
}

// ---------------- depthwise causal conv (window 3) ----------------
__global__ __launch_bounds__(256) void conv_dw(const float* __restrict__ x,
                                               const float* __restrict__ w_dw,
                                               unsigned short* __restrict__ y_bf) {
  int i = blockIdx.x * 256 + threadIdx.x;       // T*DM
  int c = i & (DM - 1);
  int t = i >> 10;
  float a = (t >= 2) ? x[i - 2 * DM] : 0.f;
  float b = (t >= 1) ? x[i - DM]     : 0.f;
  float d = x[i];
  float y = a * w_dw[c * 3] + b * w_dw[c * 3 + 1] + d * w_dw[c * 3 + 2];
  y_bf[i] = bfbits(y);
}

// ---- small GEMM: 128x128, BK=64, 4 waves, 64KB LDS (2 blocks/CU), T1+T2+T4+T5 ----
// C(MxN) = A(MxK) * B(NxK)^T.  grid: (M/128, N/128 [, z]); gridDim.x mult of 8.
// EPI 0: fp32 store; z==1 switches to A2/B2/Cf2 (batched pair)
// EPI 1: s = acc + ex0[row*ldc+col]; store fp32 Cf and bf16 Cbf (x1 = x + y@w_pw^T)
template <int EPI>
__global__ __launch_bounds__(256, 2) void gemm128s(
    const unsigned short* __restrict__ A, const unsigned short* __restrict__ A2,
    const unsigned short* __restrict__ B, const unsigned short* __restrict__ B2,
    float* __restrict__ Cf, float* __restrict__ Cf2,
    unsigned short* __restrict__ Cbf, const float* __restrict__ ex0,
    int lda, int ldb, int K, int ldc)
{
  if (EPI == 0) { if (blockIdx.z) { A = A2; B = B2; Cf = Cf2; } }

  __shared__ unsigned short As[2][128][64];
  __shared__ unsigned short Bs[2][128][64];   // 64 KiB total -> 2 blocks/CU

  // T1: XCD chunking + decode bits [m_lo:3 | m_hi x n]
  const int nwg = gridDim.x * gridDim.y;
  const int bidl = blockIdx.y * gridDim.x + blockIdx.x;
  const int chunk = nwg >> 3;
  const int swz = (bidl & 7) * chunk + (bidl >> 3);
  const int ntn = gridDim.y;
  const int rest = swz >> 3;
  const int m0 = ((rest / ntn) * 8 + (swz & 7)) << 7;
  const int n0 = (rest % ntn) << 7;

  const int tid = threadIdx.x;
  const int srow = tid >> 3;                      // 0..31
  const int scol = (tid & 7) << 3;
  const int scsw = (((tid & 7) ^ ((tid >> 3) & 7)) << 3);   // T2 source pre-swizzle
  const unsigned short* gA = A + (size_t)(m0 + srow) * lda + scsw;
  const unsigned short* gB = B + (size_t)(n0 + srow) * ldb + scsw;

  auto stage = [&](int k0, int b) {               // 8 gl_lds / thread / K-tile
    #pragma unroll
    for (int i = 0; i < 4; i++)
      gl_lds16(gA + (size_t)(i * 32) * lda + k0, &As[b][i * 32 + srow][scol]);
    #pragma unroll
    for (int i = 0; i < 4; i++)
      gl_lds16(gB + (size_t)(i * 32) * ldb + k0, &Bs[b][i * 32 + srow][scol]);
  };

  const int lane = tid & 63, wv = tid >> 6;
  const int wr = (wv >> 1) << 6, wc = (wv & 1) << 6;      // 64x64 per wave
  const int fr = lane & 15, kreg = lane >> 4, r4 = kreg << 2;
  const int c0 = ((kreg) ^ (lane & 7)) << 3;
  const int c1 = ((4 + kreg) ^ (lane & 7)) << 3;

  f32x4_v acc[4][4] = {};

  stage(0, 0);
  const int nt = K >> 6;
  for (int t = 0; t < nt; t++) {
    const int p = t & 1;
    if (t + 1 < nt) {
      stage((t + 1) << 6, p ^ 1);
      asm volatile("s_waitcnt vmcnt(8)" ::: "memory");
    } else {
      asm volatile("s_waitcnt vmcnt(0)" ::: "memory");
    }
    __builtin_amdgcn_s_barrier();
    __builtin_amdgcn_sched_barrier(0);
    bf16x8_v af[4][2], bfm[4][2];
    #pragma unroll
    for (int m = 0; m < 4; m++) {
      af[m][0] = *(const bf16x8_v*)&As[p][wr + m * 16 + fr][c0];
      af[m][1] = *(const bf16x8_v*)&As[p][wr + m * 16 + fr][c1];
    }
    #pragma unroll
    for (int n = 0; n < 4; n++) {
      bfm[n][0] = *(const bf16x8_v*)&Bs[p][wc + n * 16 + fr][c0];
      bfm[n][1] = *(const bf16x8_v*)&Bs[p][wc + n * 16 + fr][c1];
    }
    __builtin_amdgcn_s_setprio(1);
    #pragma unroll
    for (int m = 0; m < 4; m++)
      #pragma unroll
      for (int n = 0; n < 4; n++) {
        acc[m][n] = __builtin_amdgcn_mfma_f32_16x16x32_bf16(af[m][0], bfm[n][0], acc[m][n], 0, 0, 0);
        acc[m][n] = __builtin_amdgcn_mfma_f32_16x16x32_bf16(af[m][1], bfm[n][1], acc[m][n], 0, 0, 0);
      }
    __builtin_amdgcn_s_setprio(0);
    __builtin_amdgcn_s_barrier();
  }

  #pragma unroll
  for (int m = 0; m < 4; m++)
    #pragma unroll
    for (int n = 0; n < 4; n++)
      #pragma unroll
      for (int j = 0; j < 4; j++) {
        int grow = m0 + wr + m * 16 + r4 + j;
        int gcol = n0 + wc + n * 16 + fr;
        size_t off = (size_t)grow * ldc + gcol;
        if (EPI == 0) {
          Cf[off] = acc[m][n][j];
        } else {
          float s = acc[m][n][j] + ex0[off];
          Cf[off] = s; Cbf[off] = bfbits(s);
        }
      }
}

// ---- MoE GEMM 256x256, BK=64, 8 waves + fused fp32->bf16 B-staging (reg path) ----
// C(MxN) = A(MxK,bf16) * B(NxK,FP32)^T.  grid: (8, N/256 [, z]).
// A staged via gl_lds (T2 pre-swizzled source); B loaded fp32 -> cvt -> swizzled
// ds_write_b128.  One barrier per K-tile: writes published via vmcnt(0)+lgkmcnt(0).
// EPI 0: MoE-up:  silu(acc + ex0[col]) * ex1[row*4 + col>>12] -> bf16 Cbf
// EPI 1: MoE-down: atomicAdd(Cf, acc); z selects K-slice; B = w2 natural (E,d,Hid),
//        ldbf = HIDN, expert = ko>>12 (kPerZ divides 4096).
template <int EPI>
__global__ __launch_bounds__(512, 1) void gemm256(
    const unsigned short* __restrict__ A, const float* __restrict__ Bf,
    float* __restrict__ Cf, unsigned short* __restrict__ Cbf,
    const float* __restrict__ ex0, const float* __restrict__ ex1,
    int lda, int ldbf, int K, int ldc, int kPerZ)
{
  if (EPI == 1) {
    int ko = blockIdx.z * kPerZ;
    A  += ko;
    Bf += (size_t)(ko >> 12) * DM * HIDN + (ko & 4095);
    K = kPerZ;
  }

  __shared__ unsigned short As[2][256][64];   // 64 KiB
  __shared__ unsigned short Bs[2][256][64];   // 64 KiB

  int bidl = blockIdx.y * gridDim.x + blockIdx.x;
  int chunk = (gridDim.x * gridDim.y) >> 3;
  int swz = (bidl & 7) * chunk + (bidl >> 3);
  int m0 = (swz & 7) << 8, n0 = (swz >> 3) << 8;

  const int tid = threadIdx.x;
  const int srow = tid >> 3;                      // 0..63
  const int scol = (tid & 7) << 3;
  const int scsw = (((tid & 7) ^ ((tid >> 3) & 7)) << 3);
  const unsigned short* gA = A + (size_t)(m0 + srow) * lda + scsw;

  const int br = tid >> 1, bc = (tid & 1) << 5;   // B: row 0..255, col-half 0/32
  const float* gBf = Bf + (size_t)(n0 + br) * ldbf + bc;

  auto stageA = [&](int k0, int b) {              // 4 gl_lds / thread
    #pragma unroll
    for (int i = 0; i < 4; i++)
      gl_lds16(gA + (size_t)(i * 64) * lda + k0, &As[b][i * 64 + srow][scol]);
  };
  float4 bl[8];                                   // 32 fp32 of B (one row-half window)
  auto loadB = [&](int k0) {
    #pragma unroll
    for (int j = 0; j < 8; j++) bl[j] = *(const float4*)(gBf + k0 + j * 4);
  };
  auto writeB = [&](int b) {                      // cvt + T2-swizzled ds_write
    #pragma unroll
    for (int j = 0; j < 4; j++) {
      bf16x8_v w;
      w[0] = (short)bfbits(bl[2*j].x);   w[1] = (short)bfbits(bl[2*j].y);
      w[2] = (short)bfbits(bl[2*j].z);   w[3] = (short)bfbits(bl[2*j].w);
      w[4] = (short)bfbits(bl[2*j+1].x); w[5] = (short)bfbits(bl[2*j+1].y);
      w[6] = (short)bfbits(bl[2*j+1].z); w[7] = (short)bfbits(bl[2*j+1].w);
      int slot = (((bc >> 3) + j) ^ (br & 7)) << 3;
      *(bf16x8_v*)&Bs[b][br][slot] = w;
    }
  };

  const int lane = tid & 63, wv = tid >> 6;
  const int wm = wv >> 2, wn = wv & 3;            // 2M x 4N waves; 128x64 out each
  const int fr = lane & 15;
  const int kreg = lane >> 4, r4 = kreg << 2;
  const int c0 = ((kreg) ^ (lane & 7)) << 3;
  const int c1 = ((4 + kreg) ^ (lane & 7)) << 3;

  f32x4_v acc[8][4] = {};
  bf16x8_v a0[4][2], a1[4][2], bb[2][2];

  // prologue: tile 0 into buf 0
  loadB(0); stageA(0, 0); writeB(0);
  asm volatile("s_waitcnt vmcnt(0)" ::: "memory");
  asm volatile("s_waitcnt lgkmcnt(0)" ::: "memory");
  __builtin_amdgcn_s_barrier();
  __builtin_amdgcn_sched_barrier(0);

  const int nt = K >> 6;
  for (int t = 0; t < nt; t++) {
    const int p = t & 1;
    const bool pf = (t + 1 < nt);
    const int kn = (t + 1) << 6;
    if (pf) { loadB(kn); stageA(kn, p ^ 1); }     // B first so wait-on-B keeps A in flight
    // ---- compute tile t (quadrant order, reg-reuse; r5-verified body) ----
    #pragma unroll
    for (int m = 0; m < 4; m++) {
      a0[m][0] = *(const bf16x8_v*)&As[p][wm * 128 + m * 16 + fr][c0];
      a0[m][1] = *(const bf16x8_v*)&As[p][wm * 128 + m * 16 + fr][c1];
    }
    #pragma unroll
    for (int n = 0; n < 2; n++) {
      bb[n][0] = *(const bf16x8_v*)&Bs[p][wn * 64 + n * 16 + fr][c0];
      bb[n][1] = *(const bf16x8_v*)&Bs[p][wn * 64 + n * 16 + fr][c1];
    }
    __builtin_amdgcn_s_setprio(1);
    #pragma unroll
    for (int m = 0; m < 4; m++)
      #pragma unroll
      for (int n = 0; n < 2; n++) {
        acc[m][n] = __builtin_amdgcn_mfma_f32_16x16x32_bf16(a0[m][0], bb[n][0], acc[m][n], 0, 0, 0);
        acc[m][n] = __builtin_amdgcn_mfma_f32_16x16x32_bf16(a0[m][1], bb[n][1], acc[m][n], 0, 0, 0);
      }
    __builtin_amdgcn_s_setprio(0);
    #pragma unroll
    for (int m = 0; m < 4; m++) {
      a1[m][0] = *(const bf16x8_v*)&As[p][wm * 128 + 64 + m * 16 + fr][c0];
      a1[m][1] = *(const bf16x8_v*)&As[p][wm * 128 + 64 + m * 16 + fr][c1];
    }
    __builtin_amdgcn_s_setprio(1);
    #pragma unroll
    for (int m = 0; m < 4; m++)
      #pragma unroll
      for (int n = 0; n < 2; n++) {
        acc[m + 4][n] = __builtin_amdgcn_mfma_f32_16x16x32_bf16(a1[m][0], bb[n][0], acc[m + 4][n], 0, 0, 0);
        acc[m + 4][n] = __builtin_amdgcn_mfma_f32_16x16x32_bf16(a1[m][1], bb[n][1], acc[m + 4][n], 0, 0, 0);
      }
    __builtin_amdgcn_s_setprio(0);
    #pragma unroll
    for (int n = 0; n < 2; n++) {
      bb[n][0] = *(const bf16x8_v*)&Bs[p][wn * 64 + 32 + n * 16 + fr][c0];
      bb[n][1] = *(const bf16x8_v*)&Bs[p][wn * 64 + 32 + n * 16 + fr][c1];
    }
    __builtin_amdgcn_s_setprio(1);
    #pragma unroll
    for (int m = 0; m < 4; m++)
      #pragma unroll
      for (int n = 0; n < 2; n++) {
        acc[m][n + 2] = __builtin_amdgcn_mfma_f32_16x16x32_bf16(a0[m][0], bb[n][0], acc[m][n + 2], 0, 0, 0);
        acc[m][n + 2] = __builtin_amdgcn_mfma_f32_16x16x32_bf16(a0[m][1], bb[n][1], acc[m][n + 2], 0, 0, 0);
      }
    #pragma unroll
    for (int m = 0; m < 4; m++)
      #pragma unroll
      for (int n = 0; n < 2; n++) {
        acc[m + 4][n + 2] = __builtin_amdgcn_mfma_f32_16x16x32_bf16(a1[m][0], bb[n][0], acc[m + 4][n + 2], 0, 0, 0);
        acc[m + 4][n + 2] = __builtin_amdgcn_mfma_f32_16x16x32_bf16(a1[m][1], bb[n][1], acc[m + 4][n + 2], 0, 0, 0);
      }
    __builtin_amdgcn_s_setprio(0);
    // ---- publish tile t+1: B write (waits its loads), then drain A gl_lds ----
    if (pf) writeB(p ^ 1);
    asm volatile("s_waitcnt vmcnt(0)" ::: "memory");
    asm volatile("s_waitcnt lgkmcnt(0)" ::: "memory");
    __builtin_amdgcn_s_barrier();                 // WAR for buf p + publish buf p^1
    __builtin_amdgcn_sched_barrier(0);
  }

  #pragma unroll
  for (int m = 0; m < 8; m++)
    #pragma unroll
    for (int n = 0; n < 4; n++)
      #pragma unroll
      for (int j = 0; j < 4; j++) {
        int grow = m0 + wm * 128 + m * 16 + r4 + j;
        int gcol = n0 + wn * 64 + n * 16 + fr;
        size_t off = (size_t)grow * ldc + gcol;
        if (EPI == 0) {
          float c2 = acc[m][n][j] + ex0[gcol];
          float sl = c2 / (1.f + __expf(-c2));
          Cbf[off] = bfbits(sl * ex1[grow * 4 + (gcol >> 12)]);
        } else {
          atomicAdd(&Cf[off], acc[m][n][j]);
        }
      }
}

// ---------------- RoPE + elu-phi feature map ----------------
__global__ __launch_bounds__(256) void rope_phi(const float* __restrict__ qkv,
                                                unsigned short* __restrict__ qphi,
                                                unsigned short* __restrict__ kphi,
                                                unsigned short* __restrict__ vout) {
  int idx = blockIdx.x * 256 + threadIdx.x;     // T*NHD*32
  int i = idx & 31;
  int h = (idx >> 5) & 15;
  int t = idx >> 9;
  const float* row = qkv + (size_t)t * 3 * DM;
  int col = h * 64 + 2 * i;
  float q0 = row[col],          q1 = row[col + 1];
  float k0 = row[DM + col],     k1 = row[DM + col + 1];
  float v0 = row[2 * DM + col], v1 = row[2 * DM + col + 1];
  float invf = __expf(-(float)(2 * i) * (9.210340371976184f / 64.f));
  float th = (float)t * invf;
  float s, c;
  sincosf(th, &s, &c);
  float qr0 = q0 * c - q1 * s, qr1 = q0 * s + q1 * c;
  float kr0 = k0 * c - k1 * s, kr1 = k0 * s + k1 * c;
  size_t o = (size_t)t * DM + col;
  qphi[o]     = bfbits(qr0 > 0.f ? qr0 + 1.f : __expf(qr0));
  qphi[o + 1] = bfbits(qr1 > 0.f ? qr1 + 1.f : __expf(qr1));
  kphi[o]     = bfbits(kr0 > 0.f ? kr0 + 1.f : __expf(kr0));
  kphi[o + 1] = bfbits(kr1 > 0.f ? kr1 + 1.f : __expf(kr1));
  vout[o]     = bfbits(v0);
  vout[o + 1] = bfbits(v1);
}

// ---------------- chunked linear attention ----------------
// Pass A: per (h,c): KV_c^T[n][d] = sum_t V[t][n]K[t][d]  (MFMA), ksum_c[d]
__global__ __launch_bounds__(256) void kv_chunk(const unsigned short* __restrict__ kphi,
                                                const unsigned short* __restrict__ vbf,
                                                float* __restrict__ kvT,
                                                float* __restrict__ ksbuf) {
  int h = blockIdx.x & 15, c = blockIdx.x >> 4;
  __shared__ unsigned short Kt[64][136];
  __shared__ unsigned short Vt[64][136];
  int tid = threadIdx.x;
  int rr = tid >> 3, cc = (tid & 7) << 3;       // 32 rows x 64 cols per pass
  int t0 = c * CHK;
  #pragma unroll
  for (int g = 0; g < 4; g++) {
    int t = g * 32 + rr;
    bf16x8_v k8 = *(const bf16x8_v*)&kphi[(size_t)(t0 + t) * DM + h * 64 + cc];
    bf16x8_v v8 = *(const bf16x8_v*)&vbf [(size_t)(t0 + t) * DM + h * 64 + cc];
    #pragma unroll
    for (int j = 0; j < 8; j++) { Kt[cc + j][t] = (unsigned short)k8[j];
                                  Vt[cc + j][t] = (unsigned short)v8[j]; }
  }
  __syncthreads();
  int lane = tid & 63, wv = tid >> 6;
  int wr = (wv >> 1) << 5, wc = (wv & 1) << 5;  // 32x32 per wave over 64x64
  int fr = lane & 15, fk = (lane >> 4) << 3, r4 = (lane >> 4) << 2;
  f32x4_v acc[2][2] = {};
  #pragma unroll
  for (int k0 = 0; k0 < 128; k0 += 32) {
    bf16x8_v a[2], b[2];
    #pragma unroll
    for (int m = 0; m < 2; m++) a[m] = *(const bf16x8_v*)&Kt[wr + m * 16 + fr][k0 + fk];
    #pragma unroll
    for (int n = 0; n < 2; n++) b[n] = *(const bf16x8_v*)&Vt[wc + n * 16 + fr][k0 + fk];
    #pragma unroll
    for (int m = 0; m < 2; m++)
      #pragma unroll
      for (int n = 0; n < 2; n++)
        acc[m][n] = __builtin_amdgcn_mfma_f32_16x16x32_bf16(a[m], b[n], acc[m][n], 0, 0, 0);
  }
  float* kvout = kvT + (size_t)(h * NCHK + c) * 4096;   // [n][d]
  #pragma unroll
  for (int m = 0; m < 2; m++)
    #pragma unroll
    for (int n = 0; n < 2; n++)
      #pragma unroll
      for (int j = 0; j < 4; j++)
        kvout[(wc + n * 16 + fr) * 64 + (wr + m * 16 + r4 + j)] = acc[m][n][j];
  // ksum: d = tid>>2, quarter (tid&3) sums 32 of 128
  float s = 0.f;
  int d = tid >> 2, q = tid & 3;
  for (int i = 0; i < 32; i++) s += bf2f(Kt[d][q * 32 + i]);
  s += __shfl_xor(s, 1, 64); s += __shfl_xor(s, 2, 64);
  if (q == 0) ksbuf[(h * NCHK + c) * 64 + d] = s;
}

// Pass B: exclusive prefix over chunks; sT[h][c][n*64+d] bf16; kspre fp32
__global__ __launch_bounds__(256) void prefix_kv(const float* __restrict__ kvT,
                                                 const float* __restrict__ ksbuf,
                                                 unsigned short* __restrict__ sT,
                                                 float* __restrict__ kspre) {
  int idx = blockIdx.x * 256 + threadIdx.x;     // h*4096 + n*64 + d over 65536
  int h = idx >> 12, nd = idx & 4095;
  float s = 0.f;
  for (int c = 0; c < NCHK; c++) {
    size_t o = (size_t)(h * NCHK + c) * 4096 + nd;
    sT[o] = bfbits(s);
    s += kvT[o];
  }
  if (idx < NHD * 64) {                         // ksum prefix (h = idx>>6, d = idx&63)
    float ks = 0.f;
    for (int c = 0; c < NCHK; c++) {
      int o = ((idx >> 6) * NCHK + c) * 64 + (idx & 63);
      kspre[o] = ks;
      ks += ksbuf[o];
    }
  }
}

// Pass C: per (h,c): M = causal(Q K^T); attn = ([M|Q] @ [V^T;S^T]^T) / den, bf16 out
__global__ __launch_bounds__(256) void attn_chunk(const unsigned short* __restrict__ qphi,
                                                  const unsigned short* __restrict__ kphi,
                                                  const unsigned short* __restrict__ vbf,
                                                  const unsigned short* __restrict__ sT,
                                                  const float* __restrict__ kspre,
                                                  unsigned short* __restrict__ attn_bf) {
  int h = blockIdx.x & 15, c = blockIdx.x >> 4;
  __shared__ unsigned short Qs[128][72];
  __shared__ unsigned short Ks[128][72];
  __shared__ unsigned short Ms[128][200];       // cols 0..127 masked M, 128..191 Q
  __shared__ unsigned short Vt[64][200];        // cols 0..127 V^T,      128..191 S_c^T
  __shared__ float ksL[64];
  __shared__ float denL[128];                   // reciprocal denominators
  int tid = threadIdx.x;
  int t0 = c * CHK;
  int rr = tid >> 3, cc = (tid & 7) << 3;
  #pragma unroll
  for (int g = 0; g < 4; g++) {
    int t = g * 32 + rr;
    bf16x8_v q8 = *(const bf16x8_v*)&qphi[(size_t)(t0 + t) * DM + h * 64 + cc];
    bf16x8_v k8 = *(const bf16x8_v*)&kphi[(size_t)(t0 + t) * DM + h * 64 + cc];
    bf16x8_v v8 = *(const bf16x8_v*)&vbf [(size_t)(t0 + t) * DM + h * 64 + cc];
    *(bf16x8_v*)&Qs[t][cc] = q8;
    *(bf16x8_v*)&Ks[t][cc] = k8;
    *(bf16x8_v*)&Ms[t][128 + cc] = q8;
    #pragma unroll
    for (int j = 0; j < 8; j++) Vt[cc + j][t] = (unsigned short)v8[j];
  }
  #pragma unroll
  for (int g = 0; g < 2; g++) {                 // S_c^T (bf16, already [n][d])
    int e = (g * 256 + tid) * 8;
    bf16x8_v s8 = *(const bf16x8_v*)&sT[(size_t)(h * NCHK + c) * 4096 + e];
    *(bf16x8_v*)&Vt[e >> 6][128 + (e & 63)] = s8;
  }
  if (tid < 64) ksL[tid] = kspre[(h * NCHK + c) * 64 + tid];
  __syncthreads();

  int lane = tid & 63, wv = tid >> 6;
  int wr = (wv >> 1) << 6, wc = (wv & 1) << 6;  // 64x64 quadrant per wave
  int fr = lane & 15, fk = (lane >> 4) << 3, r4 = (lane >> 4) << 2;
  {
    f32x4_v acc[4][4] = {};
    #pragma unroll
    for (int k0 = 0; k0 < 64; k0 += 32) {
      bf16x8_v a[4], b[4];
      #pragma unroll
      for (int m = 0; m < 4; m++) a[m] = *(const bf16x8_v*)&Qs[wr + m * 16 + fr][k0 + fk];
      #pragma unroll
      for (int n = 0; n < 4; n++) b[n] = *(const bf16x8_v*)&Ks[wc + n * 16 + fr][k0 + fk];
      #pragma unroll
      for (int m = 0; m < 4; m++)
        #pragma unroll
        for (int n = 0; n < 4; n++)
          acc[m][n] = __builtin_amdgcn_mfma_f32_16x16x32_bf16(a[m], b[n], acc[m][n], 0, 0, 0);
    }
    #pragma unroll
    for (int m = 0; m < 4; m++)
      #pragma unroll
      for (int n = 0; n < 4; n++)
        #pragma unroll
        for (int j = 0; j < 4; j++) {
          int r = wr + m * 16 + r4 + j, col = wc + n * 16 + fr;
          Ms[r][col] = bfbits(col <= r ? acc[m][n][j] : 0.f);
        }
  }
  __syncthreads();
  // denom: 2 threads per row -> reciprocal into denL
  {
    int dr = tid >> 1, half = tid & 1;
    float s = 0.f;
    for (int i = 0; i < 64; i++) s += bf2f(Ms[dr][half * 64 + i]);
    for (int i = 0; i < 32; i++) {
      int d = half * 32 + i;
      s += bf2f(Qs[dr][d]) * ksL[d];
    }
    s += __shfl_xor(s, 1, 64);
    if (!half) denL[dr] = 1.f / (s + 1e-6f);
  }
  __syncthreads();
  // num: A = Ms (128x192), B rows = Vt (64x192), out 128x64; normalize in epilogue
  {
    int wc2 = (wv & 1) << 5;
    f32x4_v acc[4][2] = {};
    #pragma unroll
    for (int k0 = 0; k0 < 192; k0 += 32) {
      bf16x8_v a[4], b[2];
      #pragma unroll
      for (int m = 0; m < 4; m++) a[m] = *(const bf16x8_v*)&Ms[wr + m * 16 + fr][k0 + fk];
      #pragma unroll
      for (int n = 0; n < 2; n++) b[n] = *(const bf16x8_v*)&Vt[wc2 + n * 16 + fr][k0 + fk];
      #pragma unroll
      for (int m = 0; m < 4; m++)
        #pragma unroll
        for (int n = 0; n < 2; n++)
          acc[m][n] = __builtin_amdgcn_mfma_f32_16x16x32_bf16(a[m], b[n], acc[m][n], 0, 0, 0);
    }
    #pragma unroll
    for (int m = 0; m < 4; m++)
      #pragma unroll
      for (int n = 0; n < 2; n++)
        #pragma unroll
        for (int j = 0; j < 4; j++) {
          int row = wr + m * 16 + r4 + j;
          attn_bf[(size_t)(t0 + row) * DM + h * 64 + wc2 + n * 16 + fr]
              = bfbits(acc[m][n][j] * denL[row]);
        }
  }
}

// ---------------- delta = x1 - shift(x1), from bf16 ----------------
__global__ __launch_bounds__(256) void delta_cvt(const unsigned short* __restrict__ x1b,
                                                 unsigned short* __restrict__ delta_bf) {
  int i = blockIdx.x * 256 + threadIdx.x;       // over T*DM/8
  int i8 = i * 8;
  int t = i8 >> 10;
  bf16x8_v cur = *(const bf16x8_v*)&x1b[i8];
  bf16x8_v prv = t ? *(const bf16x8_v*)&x1b[i8 - DM] : cur;
  bf16x8_v o;
  #pragma unroll
  for (int j = 0; j < 8; j++)
    o[j] = (short)bfbits(bf2f((unsigned short)cur[j]) - bf2f((unsigned short)prv[j]));
  *(bf16x8_v*)&delta_bf[i8] = o;
}

// ---- gate+residual, LayerNorm, MoE router, out-init (out = x2 + sum_e gw*b2) ----
__global__ __launch_bounds__(256) void fuse_ln(const float* __restrict__ x1,
                                               const float* __restrict__ attn_o,
                                               const float* __restrict__ gate_lin,
                                               const float* __restrict__ b_gate,
                                               const float* __restrict__ ln_g,
                                               const float* __restrict__ ln_b,
                                               const float* __restrict__ w_moe,
                                               const float* __restrict__ b2,
                                               float* __restrict__ out,
                                               unsigned short* __restrict__ h_bf,
                                               float* __restrict__ gw) {
  int t = blockIdx.x;
  int tid = threadIdx.x;
  __shared__ float hrow[DM];
  __shared__ float red[16];
  float vals[4], s = 0.f, s2 = 0.f;
  #pragma unroll
  for (int j = 0; j < 4; j++) {
    int c = tid + j * 256;
    size_t ix = (size_t)t * DM + c;
    float g = gate_lin[ix] + b_gate[c];
    float sig = 1.f / (1.f + __expf(-g));
    float xv = x1[ix] + sig * attn_o[ix];
    vals[j] = xv; s += xv; s2 += xv * xv;
  }
  s = wave_sum(s); s2 = wave_sum(s2);
  int wvi = tid >> 6, l = tid & 63;
  if (l == 0) { red[wvi] = s; red[4 + wvi] = s2; }
  __syncthreads();
  s  = red[0] + red[1] + red[2] + red[3];
  s2 = red[4] + red[5] + red[6] + red[7];
  float mu = s * (1.f / DM);
  float var = s2 * (1.f / DM) - mu * mu;
  float rstd = rsqrtf(var + 1e-5f);
  #pragma unroll
  for (int j = 0; j < 4; j++) {
    int c = tid + j * 256;
    size_t ix = (size_t)t * DM + c;
    float h = (vals[j] - mu) * rstd * ln_g[c] + ln_b[c];
    h_bf[ix] = bfbits(h); hrow[c] = h;
  }
  __syncthreads();
  float dot = 0.f;                              // wave wvi handles expert wvi
  for (int i0 = l; i0 < DM; i0 += 64) dot += hrow[i0] * w_moe[wvi * DM + i0];
  dot = wave_sum(dot);
  if (l == 0) red[8 + wvi] = dot;
  __syncthreads();
  float a0 = red[8], a1 = red[9], a2 = red[10], a3 = red[11];
  float mx = fmaxf(fmaxf(a0, a1), fmaxf(a2, a3));
  float e0 = __expf(a0 - mx), e1 = __expf(a1 - mx), e2 = __expf(a2 - mx), e3 = __expf(a3 - mx);
  float inv = 1.f / (e0 + e1 + e2 + e3);
  float g0 = e0 * inv, g1 = e1 * inv, g2 = e2 * inv, g3 = e3 * inv;
  if (tid == 0) {
    gw[t * 4 + 0] = g0; gw[t * 4 + 1] = g1; gw[t * 4 + 2] = g2; gw[t * 4 + 3] = g3;
  }
  #pragma unroll
  for (int j = 0; j < 4; j++) {                 // out init: x2 + sum_e gw*b2
    int c = tid + j * 256;
    out[(size_t)t * DM + c] = vals[j] + g0 * b2[c] + g1 * b2[DM + c]
                            + g2 * b2[2 * DM + c] + g3 * b2[3 * DM + c];
  }
}

extern "C" void kernel_launch(void* const* d_in, const int* in_sizes, int n_in,
                              void* d_out, int out_size, void* d_ws, size_t ws_size,
                              hipStream_t stream) {
  const float* x      = (const float*)d_in[0];
  const float* w_dw   = (const float*)d_in[1];
  const float* w_pw   = (const float*)d_in[2];
  const float* w_qkv  = (const float*)d_in[3];
  const float* w_o    = (const float*)d_in[4];
  const float* w_gate = (const float*)d_in[5];
  const float* b_gate = (const float*)d_in[6];
  const float* ln_g   = (const float*)d_in[7];
  const float* ln_b   = (const float*)d_in[8];
  const float* w_moe  = (const float*)d_in[9];
  const float* w1     = (const float*)d_in[10];
  const float* b1     = (const float*)d_in[11];
  const float* w2     = (const float*)d_in[12];
  const float* b2     = (const float*)d_in[13];
  float* out = (float*)d_out;

  char* ws = (char*)d_ws;
  size_t off = 0;
  auto alloc = [&](size_t bytes) -> char* {
    char* p = ws + off; off += (bytes + 255) & ~(size_t)255; return p;
  };
  unsigned short* w_pw_bf   = (unsigned short*)alloc((size_t)DM * DM * 2);
  unsigned short* w_qkv_bf  = (unsigned short*)alloc((size_t)3 * DM * DM * 2);
  unsigned short* w_o_bf    = (unsigned short*)alloc((size_t)DM * DM * 2);
  unsigned short* w_gate_bf = (unsigned short*)alloc((size_t)DM * DM * 2);
  float*          x1        = (float*)alloc((size_t)TSEQ * DM * 4);
  unsigned short* x1_bf     = (unsigned short*)alloc((size_t)TSEQ * DM * 2);
  unsigned short* y_bf      = (unsigned short*)alloc((size_t)TSEQ * DM * 2);
  float*          gwb       = (float*)alloc((size_t)TSEQ * NEXP * 4);
  float*          attn_o    = (float*)alloc((size_t)TSEQ * DM * 4);
  unsigned short* delta_bf  = (unsigned short*)alloc((size_t)TSEQ * DM * 2);
  float*          gate_lin  = (float*)alloc((size_t)TSEQ * DM * 4);
  unsigned short* h_bf      = (unsigned short*)alloc((size_t)TSEQ * DM * 2);
  float*          kvT       = (float*)alloc((size_t)NHD * NCHK * 4096 * 4);        // 4 MiB
  unsigned short* sTb       = (unsigned short*)alloc((size_t)NHD * NCHK * 4096 * 2);
  float*          ksbuf     = (float*)alloc((size_t)NHD * NCHK * 64 * 4);
  float*          kspre     = (float*)alloc((size_t)NHD * NCHK * 64 * 4);
  char*           pool      = alloc((size_t)TSEQ * NMOE * 2);   // 64 MiB, aliased
  if (off > ws_size) return;  // workspace too small: fail loudly (output stays poisoned)

  // pool phase 1 (pre-MoE): qkv f32 | qphi | kphi | v | attn_bf
  float*          qkv      = (float*)pool;
  unsigned short* qphi     = (unsigned short*)(pool + (size_t)TSEQ * 3 * DM * 4);
  unsigned short* kphi     = qphi + (size_t)TSEQ * DM;
  unsigned short* vbf      = kphi + (size_t)TSEQ * DM;
  unsigned short* attn_bf  = vbf + (size_t)TSEQ * DM;
  // pool phase 2 (MoE): hidden activations, gw-prescaled, bf16 (T x 16384)
  unsigned short* hids     = (unsigned short*)pool;

  // 1) small weights -> bf16 in ONE launch (w1/w2 converted inside the MoE GEMMs)
  cvt_all<<<6144, 256, 0, stream>>>(w_pw, w_pw_bf, w_qkv, w_qkv_bf,
                                    w_o, w_o_bf, w_gate, w_gate_bf);

  // 2) conv mixer + residual (x1 = x + conv(x) @ w_pw^T)
  conv_dw<<<8192, 256, 0, stream>>>(x, w_dw, y_bf);
  gemm128s<1><<<dim3(16, 8, 1), 256, 0, stream>>>(y_bf, nullptr, w_pw_bf, nullptr,
      x1, nullptr, x1_bf, x, DM, DM, DM, DM);

  // 3) qkv projection, RoPE, feature map
  gemm128s<0><<<dim3(16, 24, 1), 256, 0, stream>>>(x1_bf, nullptr, w_qkv_bf, nullptr,
      qkv, nullptr, nullptr, nullptr, DM, DM, DM, 3 * DM);
  rope_phi<<<4096, 256, 0, stream>>>(qkv, qphi, kphi, vbf);

  // 4) chunked causal linear attention (normalize fused into pass C)
  kv_chunk<<<NHD * NCHK, 256, 0, stream>>>(kphi, vbf, kvT, ksbuf);
  prefix_kv<<<256, 256, 0, stream>>>(kvT, ksbuf, sTb, kspre);
  attn_chunk<<<NHD * NCHK, 256, 0, stream>>>(qphi, kphi, vbf, sTb, kspre, attn_bf);
  delta_cvt<<<1024, 256, 0, stream>>>(x1_bf, delta_bf);

  // 5) output projection + delta gate projection (batched GEMM)
  gemm128s<0><<<dim3(16, 8, 2), 256, 0, stream>>>(attn_bf, delta_bf, w_o_bf, w_gate_bf,
      attn_o, gate_lin, nullptr, nullptr, DM, DM, DM, DM);

  // 6) gated residual + LN + router + out-init (x2 + sum_e gw*b2)
  fuse_ln<<<2048, 256, 0, stream>>>(x1, attn_o, gate_lin, b_gate, ln_g, ln_b, w_moe,
                                    b2, out, h_bf, gwb);

  // 7) MoE: 256^2 kernels with fused fp32->bf16 B-staging
  //    up:   B = w1 (16384,1024) fp32, grid 8x64
  //    down: B = w2 (E,d,Hid) fp32 natural, grid 8x4x8 split-K, kPerZ=2048
  gemm256<0><<<dim3(8, 64, 1), 512, 0, stream>>>(h_bf, w1, nullptr, hids,
      b1, gwb, DM, DM, DM, NMOE, 0);
  gemm256<1><<<dim3(8, 4, 8), 512, 0, stream>>>(hids, w2, out, nullptr,
      nullptr, nullptr, NMOE, HIDN, NMOE, DM, NMOE / 8);
}

// Round 11
// 355.532 us; speedup vs baseline: 1.3026x; 1.3026x over previous
//
#include <hip/hip_runtime.h>
#include <hip/hip_bf16.h>

#define TSEQ 2048
#define DM   1024
#define NHD  16
#define DHD  64
#define NEXP 4
#define HIDN 4096
#define NMOE (NEXP*HIDN)   // 16384
#define CHK  128
#define NCHK (TSEQ/CHK)    // 16

typedef __attribute__((ext_vector_type(8))) short          bf16x8_v;  // 8 bf16 = 4 VGPR
typedef __attribute__((ext_vector_type(4))) float          f32x4_v;
typedef __attribute__((ext_vector_type(4))) unsigned short us4_v;

__device__ __forceinline__ unsigned short bfbits(float f) {
  __hip_bfloat16 h = __float2bfloat16(f);
  return __builtin_bit_cast(unsigned short, h);
}
__device__ __forceinline__ float bf2f(unsigned short u) {
  return __uint_as_float(((unsigned)u) << 16);
}
__device__ __forceinline__ float wave_sum(float v) {
  #pragma unroll
  for (int o = 32; o; o >>= 1) v += __shfl_xor(v, o, 64);
  return v;
}
__device__ __forceinline__ void gl_lds16(const void* g, void* l) {
  __builtin_amdgcn_global_load_lds((const __attribute__((address_space(1))) void*)g,
                                   (__attribute__((address_space(3))) void*)l, 16, 0, 0);
}

// ---------------- weight conversion (large: w1 / w2) ----------------
__global__ __launch_bounds__(256) void cvt_bf16(const float* __restrict__ in,
                                                unsigned short* __restrict__ out, int n4) {
  int i = blockIdx.x * 256 + threadIdx.x;
  if (i >= n4) return;
  float4 v = ((const float4*)in)[i];
  us4_v o; o.x = bfbits(v.x); o.y = bfbits(v.y); o.z = bfbits(v.z); o.w = bfbits(v.w);
  ((us4_v*)out)[i] = o;
}

// ---------------- merged small-weight conversion (pw|qkv|wo|wgate) ----------------
__global__ __launch_bounds__(256) void cvt_all(
    const float* __restrict__ a, unsigned short* __restrict__ oa,   // 1024 blocks
    const float* __restrict__ b, unsigned short* __restrict__ ob,   // 3072 blocks
    const float* __restrict__ c, unsigned short* __restrict__ oc,   // 1024 blocks
    const float* __restrict__ d, unsigned short* __restrict__ od) { // 1024 blocks
  int blk = blockIdx.x;
  const float* in; unsigned short* out; int base;
  if (blk < 1024)      { in = a; out = oa; base = blk; }
  else if (blk < 4096) { in = b; out = ob; base = blk - 1024; }
  else if (blk < 5120) { in = c; out = oc; base = blk - 4096; }
  else                 { in = d; out = od; base = blk - 5120; }
  int i = base * 256 + threadIdx.x;
  float4 v = ((const float4*)in)[i];
  us4_v o; o.x = bfbits(v.x); o.y = bfbits(v.y); o.z = bfbits(v.z); o.w = bfbits(v.w);
  ((us4_v*)out)[i] = o;
}

// ---------------- depthwise causal conv (window 3) ----------------
__global__ __launch_bounds__(256) void conv_dw(const float* __restrict__ x,
                                               const float* __restrict__ w_dw,
                                               unsigned short* __restrict__ y_bf) {
  int i = blockIdx.x * 256 + threadIdx.x;       // T*DM
  int c = i & (DM - 1);
  int t = i >> 10;
  float a = (t >= 2) ? x[i - 2 * DM] : 0.f;
  float b = (t >= 1) ? x[i - DM]     : 0.f;
  float d = x[i];
  float y = a * w_dw[c * 3] + b * w_dw[c * 3 + 1] + d * w_dw[c * 3 + 2];
  y_bf[i] = bfbits(y);
}

// ---- small GEMM: 128x128, BK=64, 4 waves, 64KB LDS (2 blocks/CU), T1+T2+T4+T5 ----
// C(MxN) = A(MxK) * B(NxK)^T.  grid: (M/128, N/128 [, z]); gridDim.x mult of 8.
// EPI 0: fp32 store; z==1 switches to A2/B2/Cf2 (batched pair)
// EPI 1: s = acc + ex0[row*ldc+col]; store fp32 Cf and bf16 Cbf (x1 = x + y@w_pw^T)
template <int EPI>
__global__ __launch_bounds__(256, 2) void gemm128s(
    const unsigned short* __restrict__ A, const unsigned short* __restrict__ A2,
    const unsigned short* __restrict__ B, const unsigned short* __restrict__ B2,
    float* __restrict__ Cf, float* __restrict__ Cf2,
    unsigned short* __restrict__ Cbf, const float* __restrict__ ex0,
    int lda, int ldb, int K, int ldc)
{
  if (EPI == 0) { if (blockIdx.z) { A = A2; B = B2; Cf = Cf2; } }

  __shared__ unsigned short As[2][128][64];
  __shared__ unsigned short Bs[2][128][64];   // 64 KiB total -> 2 blocks/CU

  // T1: XCD chunking + decode bits [m_lo:3 | m_hi x n]
  const int nwg = gridDim.x * gridDim.y;
  const int bidl = blockIdx.y * gridDim.x + blockIdx.x;
  const int chunk = nwg >> 3;
  const int swz = (bidl & 7) * chunk + (bidl >> 3);
  const int ntn = gridDim.y;
  const int rest = swz >> 3;
  const int m0 = ((rest / ntn) * 8 + (swz & 7)) << 7;
  const int n0 = (rest % ntn) << 7;

  const int tid = threadIdx.x;
  const int srow = tid >> 3;                      // 0..31
  const int scol = (tid & 7) << 3;
  const int scsw = (((tid & 7) ^ ((tid >> 3) & 7)) << 3);   // T2 source pre-swizzle
  const unsigned short* gA = A + (size_t)(m0 + srow) * lda + scsw;
  const unsigned short* gB = B + (size_t)(n0 + srow) * ldb + scsw;

  auto stage = [&](int k0, int b) {               // 8 gl_lds / thread / K-tile
    #pragma unroll
    for (int i = 0; i < 4; i++)
      gl_lds16(gA + (size_t)(i * 32) * lda + k0, &As[b][i * 32 + srow][scol]);
    #pragma unroll
    for (int i = 0; i < 4; i++)
      gl_lds16(gB + (size_t)(i * 32) * ldb + k0, &Bs[b][i * 32 + srow][scol]);
  };

  const int lane = tid & 63, wv = tid >> 6;
  const int wr = (wv >> 1) << 6, wc = (wv & 1) << 6;      // 64x64 per wave
  const int fr = lane & 15, kreg = lane >> 4, r4 = kreg << 2;
  const int c0 = ((kreg) ^ (lane & 7)) << 3;
  const int c1 = ((4 + kreg) ^ (lane & 7)) << 3;

  f32x4_v acc[4][4] = {};

  stage(0, 0);
  const int nt = K >> 6;
  for (int t = 0; t < nt; t++) {
    const int p = t & 1;
    if (t + 1 < nt) {
      stage((t + 1) << 6, p ^ 1);
      asm volatile("s_waitcnt vmcnt(8)" ::: "memory");
    } else {
      asm volatile("s_waitcnt vmcnt(0)" ::: "memory");
    }
    __builtin_amdgcn_s_barrier();
    __builtin_amdgcn_sched_barrier(0);
    bf16x8_v af[4][2], bfm[4][2];
    #pragma unroll
    for (int m = 0; m < 4; m++) {
      af[m][0] = *(const bf16x8_v*)&As[p][wr + m * 16 + fr][c0];
      af[m][1] = *(const bf16x8_v*)&As[p][wr + m * 16 + fr][c1];
    }
    #pragma unroll
    for (int n = 0; n < 4; n++) {
      bfm[n][0] = *(const bf16x8_v*)&Bs[p][wc + n * 16 + fr][c0];
      bfm[n][1] = *(const bf16x8_v*)&Bs[p][wc + n * 16 + fr][c1];
    }
    __builtin_amdgcn_s_setprio(1);
    #pragma unroll
    for (int m = 0; m < 4; m++)
      #pragma unroll
      for (int n = 0; n < 4; n++) {
        acc[m][n] = __builtin_amdgcn_mfma_f32_16x16x32_bf16(af[m][0], bfm[n][0], acc[m][n], 0, 0, 0);
        acc[m][n] = __builtin_amdgcn_mfma_f32_16x16x32_bf16(af[m][1], bfm[n][1], acc[m][n], 0, 0, 0);
      }
    __builtin_amdgcn_s_setprio(0);
    __builtin_amdgcn_s_barrier();
  }

  #pragma unroll
  for (int m = 0; m < 4; m++)
    #pragma unroll
    for (int n = 0; n < 4; n++)
      #pragma unroll
      for (int j = 0; j < 4; j++) {
        int grow = m0 + wr + m * 16 + r4 + j;
        int gcol = n0 + wc + n * 16 + fr;
        size_t off = (size_t)grow * ldc + gcol;
        if (EPI == 0) {
          Cf[off] = acc[m][n][j];
        } else {
          float s = acc[m][n][j] + ex0[off];
          Cf[off] = s; Cbf[off] = bfbits(s);
        }
      }
}

// ---- MoE GEMM 256x256, BK=64, 8 waves, 2-barrier counted-vmcnt + T1 + T2 + T5 ----
// (r8-verified best structure: 123/124 us).  grid: (8, N/256 [, z]).
// EPI 0: MoE-up:  silu(acc + ex0[col]) * ex1[row*4 + col>>12] -> bf16 Cbf
// EPI 1: MoE-down: atomicAdd(Cf, acc); z selects K-slice of kPerZ; B = w2 in
//        natural (E,d,Hid) layout: ldb = HIDN, expert = ko>>12 (kPerZ | 4096).
template <int EPI>
__global__ __launch_bounds__(512, 1) void gemm256(
    const unsigned short* __restrict__ A, const unsigned short* __restrict__ B,
    float* __restrict__ Cf, unsigned short* __restrict__ Cbf,
    const float* __restrict__ ex0, const float* __restrict__ ex1,
    int lda, int ldb, int K, int ldc, int kPerZ)
{
  if (EPI == 1) {
    int ko = blockIdx.z * kPerZ;
    A += ko;
    B += (size_t)(ko >> 12) * DM * HIDN + (ko & 4095);
    K = kPerZ;
  }

  __shared__ unsigned short As[2][256][64];   // 64 KiB
  __shared__ unsigned short Bs[2][256][64];   // 64 KiB

  int bidl = blockIdx.y * gridDim.x + blockIdx.x;
  int chunk = (gridDim.x * gridDim.y) >> 3;
  int swz = (bidl & 7) * chunk + (bidl >> 3);
  int m0 = (swz & 7) << 8, n0 = (swz >> 3) << 8;

  const int tid = threadIdx.x;
  const int srow = tid >> 3;                      // 0..63
  const int scol = (tid & 7) << 3;
  const int scsw = (((tid & 7) ^ ((tid >> 3) & 7)) << 3);
  const unsigned short* gA = A + (size_t)(m0 + srow) * lda + scsw;
  const unsigned short* gB = B + (size_t)(n0 + srow) * ldb + scsw;

  auto stageA = [&](int k0, int b) {
    #pragma unroll
    for (int i = 0; i < 4; i++)
      gl_lds16(gA + (size_t)(i * 64) * lda + k0, &As[b][i * 64 + srow][scol]);
  };
  auto stageB = [&](int k0, int b) {
    #pragma unroll
    for (int i = 0; i < 4; i++)
      gl_lds16(gB + (size_t)(i * 64) * ldb + k0, &Bs[b][i * 64 + srow][scol]);
  };

  const int lane = tid & 63, wv = tid >> 6;
  const int wm = wv >> 2, wn = wv & 3;            // 2M x 4N waves; 128x64 out each
  const int fr = lane & 15;
  const int kreg = lane >> 4, r4 = kreg << 2;
  const int c0 = ((kreg) ^ (lane & 7)) << 3;
  const int c1 = ((4 + kreg) ^ (lane & 7)) << 3;

  f32x4_v acc[8][4] = {};
  bf16x8_v a0[4][2], a1[4][2], bb[2][2];

  stageA(0, 0); stageB(0, 0);
  const int nt = K >> 6;
  for (int t = 0; t < nt; t++) {
    const int p = t & 1;
    if (t + 1 < nt) {
      stageA((t + 1) << 6, p ^ 1);
      asm volatile("s_waitcnt vmcnt(4)" ::: "memory");
    } else {
      asm volatile("s_waitcnt vmcnt(0)" ::: "memory");
    }
    __builtin_amdgcn_s_barrier();
    __builtin_amdgcn_sched_barrier(0);
    #pragma unroll
    for (int m = 0; m < 4; m++) {
      a0[m][0] = *(const bf16x8_v*)&As[p][wm * 128 + m * 16 + fr][c0];
      a0[m][1] = *(const bf16x8_v*)&As[p][wm * 128 + m * 16 + fr][c1];
    }
    #pragma unroll
    for (int n = 0; n < 2; n++) {
      bb[n][0] = *(const bf16x8_v*)&Bs[p][wn * 64 + n * 16 + fr][c0];
      bb[n][1] = *(const bf16x8_v*)&Bs[p][wn * 64 + n * 16 + fr][c1];
    }
    __builtin_amdgcn_s_setprio(1);
    #pragma unroll
    for (int m = 0; m < 4; m++)
      #pragma unroll
      for (int n = 0; n < 2; n++) {
        acc[m][n] = __builtin_amdgcn_mfma_f32_16x16x32_bf16(a0[m][0], bb[n][0], acc[m][n], 0, 0, 0);
        acc[m][n] = __builtin_amdgcn_mfma_f32_16x16x32_bf16(a0[m][1], bb[n][1], acc[m][n], 0, 0, 0);
      }
    __builtin_amdgcn_s_setprio(0);
    #pragma unroll
    for (int m = 0; m < 4; m++) {
      a1[m][0] = *(const bf16x8_v*)&As[p][wm * 128 + 64 + m * 16 + fr][c0];
      a1[m][1] = *(const bf16x8_v*)&As[p][wm * 128 + 64 + m * 16 + fr][c1];
    }
    __builtin_amdgcn_s_setprio(1);
    #pragma unroll
    for (int m = 0; m < 4; m++)
      #pragma unroll
      for (int n = 0; n < 2; n++) {
        acc[m + 4][n] = __builtin_amdgcn_mfma_f32_16x16x32_bf16(a1[m][0], bb[n][0], acc[m + 4][n], 0, 0, 0);
        acc[m + 4][n] = __builtin_amdgcn_mfma_f32_16x16x32_bf16(a1[m][1], bb[n][1], acc[m + 4][n], 0, 0, 0);
      }
    __builtin_amdgcn_s_setprio(0);
    #pragma unroll
    for (int n = 0; n < 2; n++) {
      bb[n][0] = *(const bf16x8_v*)&Bs[p][wn * 64 + 32 + n * 16 + fr][c0];
      bb[n][1] = *(const bf16x8_v*)&Bs[p][wn * 64 + 32 + n * 16 + fr][c1];
    }
    if (t + 1 < nt) stageB((t + 1) << 6, p ^ 1);
    __builtin_amdgcn_s_setprio(1);
    #pragma unroll
    for (int m = 0; m < 4; m++)
      #pragma unroll
      for (int n = 0; n < 2; n++) {
        acc[m][n + 2] = __builtin_amdgcn_mfma_f32_16x16x32_bf16(a0[m][0], bb[n][0], acc[m][n + 2], 0, 0, 0);
        acc[m][n + 2] = __builtin_amdgcn_mfma_f32_16x16x32_bf16(a0[m][1], bb[n][1], acc[m][n + 2], 0, 0, 0);
      }
    #pragma unroll
    for (int m = 0; m < 4; m++)
      #pragma unroll
      for (int n = 0; n < 2; n++) {
        acc[m + 4][n + 2] = __builtin_amdgcn_mfma_f32_16x16x32_bf16(a1[m][0], bb[n][0], acc[m + 4][n + 2], 0, 0, 0);
        acc[m + 4][n + 2] = __builtin_amdgcn_mfma_f32_16x16x32_bf16(a1[m][1], bb[n][1], acc[m + 4][n + 2], 0, 0, 0);
      }
    __builtin_amdgcn_s_setprio(0);
    __builtin_amdgcn_s_barrier();
  }

  #pragma unroll
  for (int m = 0; m < 8; m++)
    #pragma unroll
    for (int n = 0; n < 4; n++)
      #pragma unroll
      for (int j = 0; j < 4; j++) {
        int grow = m0 + wm * 128 + m * 16 + r4 + j;
        int gcol = n0 + wn * 64 + n * 16 + fr;
        size_t off = (size_t)grow * ldc + gcol;
        if (EPI == 0) {
          float c2 = acc[m][n][j] + ex0[gcol];
          float sl = c2 / (1.f + __expf(-c2));
          Cbf[off] = bfbits(sl * ex1[grow * 4 + (gcol >> 12)]);
        } else {
          atomicAdd(&Cf[off], acc[m][n][j]);
        }
      }
}

// ---------------- RoPE + elu-phi feature map ----------------
__global__ __launch_bounds__(256) void rope_phi(const float* __restrict__ qkv,
                                                unsigned short* __restrict__ qphi,
                                                unsigned short* __restrict__ kphi,
                                                unsigned short* __restrict__ vout) {
  int idx = blockIdx.x * 256 + threadIdx.x;     // T*NHD*32
  int i = idx & 31;
  int h = (idx >> 5) & 15;
  int t = idx >> 9;
  const float* row = qkv + (size_t)t * 3 * DM;
  int col = h * 64 + 2 * i;
  float q0 = row[col],          q1 = row[col + 1];
  float k0 = row[DM + col],     k1 = row[DM + col + 1];
  float v0 = row[2 * DM + col], v1 = row[2 * DM + col + 1];
  float invf = __expf(-(float)(2 * i) * (9.210340371976184f / 64.f));
  float th = (float)t * invf;
  float s, c;
  sincosf(th, &s, &c);
  float qr0 = q0 * c - q1 * s, qr1 = q0 * s + q1 * c;
  float kr0 = k0 * c - k1 * s, kr1 = k0 * s + k1 * c;
  size_t o = (size_t)t * DM + col;
  qphi[o]     = bfbits(qr0 > 0.f ? qr0 + 1.f : __expf(qr0));
  qphi[o + 1] = bfbits(qr1 > 0.f ? qr1 + 1.f : __expf(qr1));
  kphi[o]     = bfbits(kr0 > 0.f ? kr0 + 1.f : __expf(kr0));
  kphi[o + 1] = bfbits(kr1 > 0.f ? kr1 + 1.f : __expf(kr1));
  vout[o]     = bfbits(v0);
  vout[o + 1] = bfbits(v1);
}

// ---------------- chunked linear attention ----------------
// Pass A: per (h,c): KV_c^T[n][d] = sum_t V[t][n]K[t][d]  (MFMA), ksum_c[d]
__global__ __launch_bounds__(256) void kv_chunk(const unsigned short* __restrict__ kphi,
                                                const unsigned short* __restrict__ vbf,
                                                float* __restrict__ kvT,
                                                float* __restrict__ ksbuf) {
  int h = blockIdx.x & 15, c = blockIdx.x >> 4;
  __shared__ unsigned short Kt[64][136];
  __shared__ unsigned short Vt[64][136];
  int tid = threadIdx.x;
  int rr = tid >> 3, cc = (tid & 7) << 3;       // 32 rows x 64 cols per pass
  int t0 = c * CHK;
  #pragma unroll
  for (int g = 0; g < 4; g++) {
    int t = g * 32 + rr;
    bf16x8_v k8 = *(const bf16x8_v*)&kphi[(size_t)(t0 + t) * DM + h * 64 + cc];
    bf16x8_v v8 = *(const bf16x8_v*)&vbf [(size_t)(t0 + t) * DM + h * 64 + cc];
    #pragma unroll
    for (int j = 0; j < 8; j++) { Kt[cc + j][t] = (unsigned short)k8[j];
                                  Vt[cc + j][t] = (unsigned short)v8[j]; }
  }
  __syncthreads();
  int lane = tid & 63, wv = tid >> 6;
  int wr = (wv >> 1) << 5, wc = (wv & 1) << 5;  // 32x32 per wave over 64x64
  int fr = lane & 15, fk = (lane >> 4) << 3, r4 = (lane >> 4) << 2;
  f32x4_v acc[2][2] = {};
  #pragma unroll
  for (int k0 = 0; k0 < 128; k0 += 32) {
    bf16x8_v a[2], b[2];
    #pragma unroll
    for (int m = 0; m < 2; m++) a[m] = *(const bf16x8_v*)&Kt[wr + m * 16 + fr][k0 + fk];
    #pragma unroll
    for (int n = 0; n < 2; n++) b[n] = *(const bf16x8_v*)&Vt[wc + n * 16 + fr][k0 + fk];
    #pragma unroll
    for (int m = 0; m < 2; m++)
      #pragma unroll
      for (int n = 0; n < 2; n++)
        acc[m][n] = __builtin_amdgcn_mfma_f32_16x16x32_bf16(a[m], b[n], acc[m][n], 0, 0, 0);
  }
  float* kvout = kvT + (size_t)(h * NCHK + c) * 4096;   // [n][d]
  #pragma unroll
  for (int m = 0; m < 2; m++)
    #pragma unroll
    for (int n = 0; n < 2; n++)
      #pragma unroll
      for (int j = 0; j < 4; j++)
        kvout[(wc + n * 16 + fr) * 64 + (wr + m * 16 + r4 + j)] = acc[m][n][j];
  // ksum: d = tid>>2, quarter (tid&3) sums 32 of 128
  float s = 0.f;
  int d = tid >> 2, q = tid & 3;
  for (int i = 0; i < 32; i++) s += bf2f(Kt[d][q * 32 + i]);
  s += __shfl_xor(s, 1, 64); s += __shfl_xor(s, 2, 64);
  if (q == 0) ksbuf[(h * NCHK + c) * 64 + d] = s;
}

// Pass B: exclusive prefix over chunks; sT[h][c][n*64+d] bf16; kspre fp32
__global__ __launch_bounds__(256) void prefix_kv(const float* __restrict__ kvT,
                                                 const float* __restrict__ ksbuf,
                                                 unsigned short* __restrict__ sT,
                                                 float* __restrict__ kspre) {
  int idx = blockIdx.x * 256 + threadIdx.x;     // h*4096 + n*64 + d over 65536
  int h = idx >> 12, nd = idx & 4095;
  float s = 0.f;
  for (int c = 0; c < NCHK; c++) {
    size_t o = (size_t)(h * NCHK + c) * 4096 + nd;
    sT[o] = bfbits(s);
    s += kvT[o];
  }
  if (idx < NHD * 64) {                         // ksum prefix (h = idx>>6, d = idx&63)
    float ks = 0.f;
    for (int c = 0; c < NCHK; c++) {
      int o = ((idx >> 6) * NCHK + c) * 64 + (idx & 63);
      kspre[o] = ks;
      ks += ksbuf[o];
    }
  }
}

// Pass C: per (h,c): M = causal(Q K^T); attn = ([M|Q] @ [V^T;S^T]^T) / den, bf16 out
__global__ __launch_bounds__(256) void attn_chunk(const unsigned short* __restrict__ qphi,
                                                  const unsigned short* __restrict__ kphi,
                                                  const unsigned short* __restrict__ vbf,
                                                  const unsigned short* __restrict__ sT,
                                                  const float* __restrict__ kspre,
                                                  unsigned short* __restrict__ attn_bf) {
  int h = blockIdx.x & 15, c = blockIdx.x >> 4;
  __shared__ unsigned short Qs[128][72];
  __shared__ unsigned short Ks[128][72];
  __shared__ unsigned short Ms[128][200];       // cols 0..127 masked M, 128..191 Q
  __shared__ unsigned short Vt[64][200];        // cols 0..127 V^T,      128..191 S_c^T
  __shared__ float ksL[64];
  __shared__ float denL[128];                   // reciprocal denominators
  int tid = threadIdx.x;
  int t0 = c * CHK;
  int rr = tid >> 3, cc = (tid & 7) << 3;
  #pragma unroll
  for (int g = 0; g < 4; g++) {
    int t = g * 32 + rr;
    bf16x8_v q8 = *(const bf16x8_v*)&qphi[(size_t)(t0 + t) * DM + h * 64 + cc];
    bf16x8_v k8 = *(const bf16x8_v*)&kphi[(size_t)(t0 + t) * DM + h * 64 + cc];
    bf16x8_v v8 = *(const bf16x8_v*)&vbf [(size_t)(t0 + t) * DM + h * 64 + cc];
    *(bf16x8_v*)&Qs[t][cc] = q8;
    *(bf16x8_v*)&Ks[t][cc] = k8;
    *(bf16x8_v*)&Ms[t][128 + cc] = q8;
    #pragma unroll
    for (int j = 0; j < 8; j++) Vt[cc + j][t] = (unsigned short)v8[j];
  }
  #pragma unroll
  for (int g = 0; g < 2; g++) {                 // S_c^T (bf16, already [n][d])
    int e = (g * 256 + tid) * 8;
    bf16x8_v s8 = *(const bf16x8_v*)&sT[(size_t)(h * NCHK + c) * 4096 + e];
    *(bf16x8_v*)&Vt[e >> 6][128 + (e & 63)] = s8;
  }
  if (tid < 64) ksL[tid] = kspre[(h * NCHK + c) * 64 + tid];
  __syncthreads();

  int lane = tid & 63, wv = tid >> 6;
  int wr = (wv >> 1) << 6, wc = (wv & 1) << 6;  // 64x64 quadrant per wave
  int fr = lane & 15, fk = (lane >> 4) << 3, r4 = (lane >> 4) << 2;
  {
    f32x4_v acc[4][4] = {};
    #pragma unroll
    for (int k0 = 0; k0 < 64; k0 += 32) {
      bf16x8_v a[4], b[4];
      #pragma unroll
      for (int m = 0; m < 4; m++) a[m] = *(const bf16x8_v*)&Qs[wr + m * 16 + fr][k0 + fk];
      #pragma unroll
      for (int n = 0; n < 4; n++) b[n] = *(const bf16x8_v*)&Ks[wc + n * 16 + fr][k0 + fk];
      #pragma unroll
      for (int m = 0; m < 4; m++)
        #pragma unroll
        for (int n = 0; n < 4; n++)
          acc[m][n] = __builtin_amdgcn_mfma_f32_16x16x32_bf16(a[m], b[n], acc[m][n], 0, 0, 0);
    }
    #pragma unroll
    for (int m = 0; m < 4; m++)
      #pragma unroll
      for (int n = 0; n < 4; n++)
        #pragma unroll
        for (int j = 0; j < 4; j++) {
          int r = wr + m * 16 + r4 + j, col = wc + n * 16 + fr;
          Ms[r][col] = bfbits(col <= r ? acc[m][n][j] : 0.f);
        }
  }
  __syncthreads();
  // denom: 2 threads per row -> reciprocal into denL
  {
    int dr = tid >> 1, half = tid & 1;
    float s = 0.f;
    for (int i = 0; i < 64; i++) s += bf2f(Ms[dr][half * 64 + i]);
    for (int i = 0; i < 32; i++) {
      int d = half * 32 + i;
      s += bf2f(Qs[dr][d]) * ksL[d];
    }
    s += __shfl_xor(s, 1, 64);
    if (!half) denL[dr] = 1.f / (s + 1e-6f);
  }
  __syncthreads();
  // num: A = Ms (128x192), B rows = Vt (64x192), out 128x64; normalize in epilogue
  {
    int wc2 = (wv & 1) << 5;
    f32x4_v acc[4][2] = {};
    #pragma unroll
    for (int k0 = 0; k0 < 192; k0 += 32) {
      bf16x8_v a[4], b[2];
      #pragma unroll
      for (int m = 0; m < 4; m++) a[m] = *(const bf16x8_v*)&Ms[wr + m * 16 + fr][k0 + fk];
      #pragma unroll
      for (int n = 0; n < 2; n++) b[n] = *(const bf16x8_v*)&Vt[wc2 + n * 16 + fr][k0 + fk];
      #pragma unroll
      for (int m = 0; m < 4; m++)
        #pragma unroll
        for (int n = 0; n < 2; n++)
          acc[m][n] = __builtin_amdgcn_mfma_f32_16x16x32_bf16(a[m], b[n], acc[m][n], 0, 0, 0);
    }
    #pragma unroll
    for (int m = 0; m < 4; m++)
      #pragma unroll
      for (int n = 0; n < 2; n++)
        #pragma unroll
        for (int j = 0; j < 4; j++) {
          int row = wr + m * 16 + r4 + j;
          attn_bf[(size_t)(t0 + row) * DM + h * 64 + wc2 + n * 16 + fr]
              = bfbits(acc[m][n][j] * denL[row]);
        }
  }
}

// ---------------- delta = x1 - shift(x1), from bf16 ----------------
__global__ __launch_bounds__(256) void delta_cvt(const unsigned short* __restrict__ x1b,
                                                 unsigned short* __restrict__ delta_bf) {
  int i = blockIdx.x * 256 + threadIdx.x;       // over T*DM/8
  int i8 = i * 8;
  int t = i8 >> 10;
  bf16x8_v cur = *(const bf16x8_v*)&x1b[i8];
  bf16x8_v prv = t ? *(const bf16x8_v*)&x1b[i8 - DM] : cur;
  bf16x8_v o;
  #pragma unroll
  for (int j = 0; j < 8; j++)
    o[j] = (short)bfbits(bf2f((unsigned short)cur[j]) - bf2f((unsigned short)prv[j]));
  *(bf16x8_v*)&delta_bf[i8] = o;
}

// ---- gate+residual, LayerNorm, MoE router, out-init (out = x2 + sum_e gw*b2) ----
__global__ __launch_bounds__(256) void fuse_ln(const float* __restrict__ x1,
                                               const float* __restrict__ attn_o,
                                               const float* __restrict__ gate_lin,
                                               const float* __restrict__ b_gate,
                                               const float* __restrict__ ln_g,
                                               const float* __restrict__ ln_b,
                                               const float* __restrict__ w_moe,
                                               const float* __restrict__ b2,
                                               float* __restrict__ out,
                                               unsigned short* __restrict__ h_bf,
                                               float* __restrict__ gw) {
  int t = blockIdx.x;
  int tid = threadIdx.x;
  __shared__ float hrow[DM];
  __shared__ float red[16];
  float vals[4], s = 0.f, s2 = 0.f;
  #pragma unroll
  for (int j = 0; j < 4; j++) {
    int c = tid + j * 256;
    size_t ix = (size_t)t * DM + c;
    float g = gate_lin[ix] + b_gate[c];
    float sig = 1.f / (1.f + __expf(-g));
    float xv = x1[ix] + sig * attn_o[ix];
    vals[j] = xv; s += xv; s2 += xv * xv;
  }
  s = wave_sum(s); s2 = wave_sum(s2);
  int wvi = tid >> 6, l = tid & 63;
  if (l == 0) { red[wvi] = s; red[4 + wvi] = s2; }
  __syncthreads();
  s  = red[0] + red[1] + red[2] + red[3];
  s2 = red[4] + red[5] + red[6] + red[7];
  float mu = s * (1.f / DM);
  float var = s2 * (1.f / DM) - mu * mu;
  float rstd = rsqrtf(var + 1e-5f);
  #pragma unroll
  for (int j = 0; j < 4; j++) {
    int c = tid + j * 256;
    size_t ix = (size_t)t * DM + c;
    float h = (vals[j] - mu) * rstd * ln_g[c] + ln_b[c];
    h_bf[ix] = bfbits(h); hrow[c] = h;
  }
  __syncthreads();
  float dot = 0.f;                              // wave wvi handles expert wvi
  for (int i0 = l; i0 < DM; i0 += 64) dot += hrow[i0] * w_moe[wvi * DM + i0];
  dot = wave_sum(dot);
  if (l == 0) red[8 + wvi] = dot;
  __syncthreads();
  float a0 = red[8], a1 = red[9], a2 = red[10], a3 = red[11];
  float mx = fmaxf(fmaxf(a0, a1), fmaxf(a2, a3));
  float e0 = __expf(a0 - mx), e1 = __expf(a1 - mx), e2 = __expf(a2 - mx), e3 = __expf(a3 - mx);
  float inv = 1.f / (e0 + e1 + e2 + e3);
  float g0 = e0 * inv, g1 = e1 * inv, g2 = e2 * inv, g3 = e3 * inv;
  if (tid == 0) {
    gw[t * 4 + 0] = g0; gw[t * 4 + 1] = g1; gw[t * 4 + 2] = g2; gw[t * 4 + 3] = g3;
  }
  #pragma unroll
  for (int j = 0; j < 4; j++) {                 // out init: x2 + sum_e gw*b2
    int c = tid + j * 256;
    out[(size_t)t * DM + c] = vals[j] + g0 * b2[c] + g1 * b2[DM + c]
                            + g2 * b2[2 * DM + c] + g3 * b2[3 * DM + c];
  }
}

extern "C" void kernel_launch(void* const* d_in, const int* in_sizes, int n_in,
                              void* d_out, int out_size, void* d_ws, size_t ws_size,
                              hipStream_t stream) {
  const float* x      = (const float*)d_in[0];
  const float* w_dw   = (const float*)d_in[1];
  const float* w_pw   = (const float*)d_in[2];
  const float* w_qkv  = (const float*)d_in[3];
  const float* w_o    = (const float*)d_in[4];
  const float* w_gate = (const float*)d_in[5];
  const float* b_gate = (const float*)d_in[6];
  const float* ln_g   = (const float*)d_in[7];
  const float* ln_b   = (const float*)d_in[8];
  const float* w_moe  = (const float*)d_in[9];
  const float* w1     = (const float*)d_in[10];
  const float* b1     = (const float*)d_in[11];
  const float* w2     = (const float*)d_in[12];
  const float* b2     = (const float*)d_in[13];
  float* out = (float*)d_out;

  char* ws = (char*)d_ws;
  size_t off = 0;
  auto alloc = [&](size_t bytes) -> char* {
    char* p = ws + off; off += (bytes + 255) & ~(size_t)255; return p;
  };
  unsigned short* w_pw_bf   = (unsigned short*)alloc((size_t)DM * DM * 2);
  unsigned short* w_qkv_bf  = (unsigned short*)alloc((size_t)3 * DM * DM * 2);
  unsigned short* w_o_bf    = (unsigned short*)alloc((size_t)DM * DM * 2);
  unsigned short* w_gate_bf = (unsigned short*)alloc((size_t)DM * DM * 2);
  unsigned short* w1_bf     = (unsigned short*)alloc((size_t)NMOE * DM * 2);
  unsigned short* w2_bf     = (unsigned short*)alloc((size_t)NEXP * DM * HIDN * 2);  // natural layout
  float*          x1        = (float*)alloc((size_t)TSEQ * DM * 4);
  unsigned short* x1_bf     = (unsigned short*)alloc((size_t)TSEQ * DM * 2);
  unsigned short* y_bf      = (unsigned short*)alloc((size_t)TSEQ * DM * 2);
  float*          gwb       = (float*)alloc((size_t)TSEQ * NEXP * 4);
  float*          attn_o    = (float*)alloc((size_t)TSEQ * DM * 4);
  unsigned short* delta_bf  = (unsigned short*)alloc((size_t)TSEQ * DM * 2);
  float*          gate_lin  = (float*)alloc((size_t)TSEQ * DM * 4);
  unsigned short* h_bf      = (unsigned short*)alloc((size_t)TSEQ * DM * 2);
  float*          kvT       = (float*)alloc((size_t)NHD * NCHK * 4096 * 4);        // 4 MiB
  unsigned short* sTb       = (unsigned short*)alloc((size_t)NHD * NCHK * 4096 * 2);
  float*          ksbuf     = (float*)alloc((size_t)NHD * NCHK * 64 * 4);
  float*          kspre     = (float*)alloc((size_t)NHD * NCHK * 64 * 4);
  char*           pool      = alloc((size_t)TSEQ * NMOE * 2);   // 64 MiB, aliased
  if (off > ws_size) return;  // workspace too small: fail loudly (output stays poisoned)

  // pool phase 1 (pre-MoE): qkv f32 | qphi | kphi | v | attn_bf
  float*          qkv      = (float*)pool;
  unsigned short* qphi     = (unsigned short*)(pool + (size_t)TSEQ * 3 * DM * 4);
  unsigned short* kphi     = qphi + (size_t)TSEQ * DM;
  unsigned short* vbf      = kphi + (size_t)TSEQ * DM;
  unsigned short* attn_bf  = vbf + (size_t)TSEQ * DM;
  // pool phase 2 (MoE): hidden activations, gw-prescaled, bf16 (T x 16384)
  unsigned short* hids     = (unsigned short*)pool;

  // 1) weights -> bf16 (small weights merged; w2 stays natural (E,d,Hid))
  cvt_all<<<6144, 256, 0, stream>>>(w_pw, w_pw_bf, w_qkv, w_qkv_bf,
                                    w_o, w_o_bf, w_gate, w_gate_bf);
  cvt_bf16<<<16384, 256, 0, stream>>>(w1, w1_bf, NMOE * DM / 4);
  cvt_bf16<<<16384, 256, 0, stream>>>(w2, w2_bf, NEXP * DM * HIDN / 4);

  // 2) conv mixer + residual (x1 = x + conv(x) @ w_pw^T)
  conv_dw<<<8192, 256, 0, stream>>>(x, w_dw, y_bf);
  gemm128s<1><<<dim3(16, 8, 1), 256, 0, stream>>>(y_bf, nullptr, w_pw_bf, nullptr,
      x1, nullptr, x1_bf, x, DM, DM, DM, DM);

  // 3) qkv projection, RoPE, feature map
  gemm128s<0><<<dim3(16, 24, 1), 256, 0, stream>>>(x1_bf, nullptr, w_qkv_bf, nullptr,
      qkv, nullptr, nullptr, nullptr, DM, DM, DM, 3 * DM);
  rope_phi<<<4096, 256, 0, stream>>>(qkv, qphi, kphi, vbf);

  // 4) chunked causal linear attention (normalize fused into pass C)
  kv_chunk<<<NHD * NCHK, 256, 0, stream>>>(kphi, vbf, kvT, ksbuf);
  prefix_kv<<<256, 256, 0, stream>>>(kvT, ksbuf, sTb, kspre);
  attn_chunk<<<NHD * NCHK, 256, 0, stream>>>(qphi, kphi, vbf, sTb, kspre, attn_bf);
  delta_cvt<<<1024, 256, 0, stream>>>(x1_bf, delta_bf);

  // 5) output projection + delta gate projection (batched GEMM)
  gemm128s<0><<<dim3(16, 8, 2), 256, 0, stream>>>(attn_bf, delta_bf, w_o_bf, w_gate_bf,
      attn_o, gate_lin, nullptr, nullptr, DM, DM, DM, DM);

  // 6) gated residual + LN + router + out-init (x2 + sum_e gw*b2)
  fuse_ln<<<2048, 256, 0, stream>>>(x1, attn_o, gate_lin, b_gate, ln_g, ln_b, w_moe,
                                    b2, out, h_bf, gwb);

  // 7) MoE: r8-verified 256^2 kernels (up: grid 8x64; down: grid 8x4x8 split-K,
  //    w2 natural layout, ldb = HIDN)
  gemm256<0><<<dim3(8, 64, 1), 512, 0, stream>>>(h_bf, w1_bf, nullptr, hids,
      b1, gwb, DM, DM, DM, NMOE, 0);
  gemm256<1><<<dim3(8, 4, 8), 512, 0, stream>>>(hids, w2_bf, out, nullptr,
      nullptr, nullptr, NMOE, HIDN, NMOE, DM, NMOE / 8);
}